// Round 1
// baseline (111.340 us; speedup 1.0000x reference)
//
#include <hip/hip_runtime.h>

// dist[b,h,w,o] = ||x[b,h,w,:]||^2 + ||omega[o,:]||^2 - 2 * x.omega
// M = 16*128*128 = 262144 pixels, O = 256 protos, D = 64.
// Strategy: bf16 MFMA GEMM for x.omega (memory-bound problem; MFMA makes
// compute negligible), fp32 exact x2/p2, fused epilogue.

typedef __attribute__((ext_vector_type(4))) float f32x4;
typedef __attribute__((ext_vector_type(8))) short s16x8;

__device__ __forceinline__ unsigned short f2bf(float f) {
    // round-to-nearest-even fp32 -> bf16 (inputs are finite, no NaN care)
    unsigned u = __builtin_bit_cast(unsigned, f);
    u += 0x7FFFu + ((u >> 16) & 1u);
    return (unsigned short)(u >> 16);
}

constexpr int D_ = 64;
constexpr int O_ = 256;
constexpr int M_ = 16 * 128 * 128;          // 262144
constexpr int ROWS_PER_BLOCK = 512;          // 8 iters * 4 waves * 16 rows
constexpr int ITERS = 8;

__global__ __launch_bounds__(256, 2) void dist_kernel(
    const float* __restrict__ x,
    const float* __restrict__ om,
    float* __restrict__ out)
{
    const int tid  = threadIdx.x;
    const int wave = tid >> 6;
    const int lane = tid & 63;
    const int lr   = lane & 15;   // row-in-tile (A) / proto-in-tile (B) / out col
    const int lg   = lane >> 4;   // 0..3 lane group
    const int lk   = lg * 8;      // k base offset of this lane's fragment

    // ---------------- one-time: omega -> B fragments (all 256 protos) + p2 ----
    s16x8 Bf[16][2];   // [n-tile][k-step]
    float p2[16];
#pragma unroll
    for (int t = 0; t < 16; ++t) {
        float p2p = 0.f;
#pragma unroll
        for (int s = 0; s < 2; ++s) {
            const float* src = om + (t * 16 + lr) * D_ + s * 32 + lk;
            float4 v0 = *(const float4*)(src);
            float4 v1 = *(const float4*)(src + 4);
            float v[8] = {v0.x, v0.y, v0.z, v0.w, v1.x, v1.y, v1.z, v1.w};
            s16x8 f;
#pragma unroll
            for (int j = 0; j < 8; ++j) {
                f[j] = (short)f2bf(v[j]);
                p2p += v[j] * v[j];
            }
            Bf[t][s] = f;
        }
        // this lane holds 16 of the 64 k-values of proto (t*16+lr); reduce
        // partial sum-of-squares across the 4 lane groups holding that proto.
        p2p += __shfl_xor(p2p, 16);
        p2p += __shfl_xor(p2p, 32);
        p2[t] = p2p;
    }

    // ---------------- steady state: 16 rows per wave per iteration ----------
    for (int it = 0; it < ITERS; ++it) {
        const int rbase = blockIdx.x * ROWS_PER_BLOCK + it * 64 + wave * 16;

        // A load: lane holds row (rbase+lr), k = lk..lk+7 and 32+lk..32+lk+7
        const float* xs = x + (rbase + lr) * D_ + lk;
        float4 a0 = *(const float4*)(xs);
        float4 a1 = *(const float4*)(xs + 4);
        float4 a2 = *(const float4*)(xs + 32);
        float4 a3 = *(const float4*)(xs + 36);
        float av[16] = {a0.x, a0.y, a0.z, a0.w, a1.x, a1.y, a1.z, a1.w,
                        a2.x, a2.y, a2.z, a2.w, a3.x, a3.y, a3.z, a3.w};
        s16x8 Af[2];
        float x2p = 0.f;
#pragma unroll
        for (int j = 0; j < 8; ++j) {
            Af[0][j] = (short)f2bf(av[j]);
            Af[1][j] = (short)f2bf(av[8 + j]);
            x2p += av[j] * av[j] + av[8 + j] * av[8 + j];
        }
        // full ||x||^2 for row (rbase+lr), replicated in all 4 lane groups
        x2p += __shfl_xor(x2p, 16);
        x2p += __shfl_xor(x2p, 32);
        // C/D layout: row = lg*4 + j  -> fetch x2 of that row (held by lane lg*4+j)
        float x2r[4];
#pragma unroll
        for (int j = 0; j < 4; ++j)
            x2r[j] = __shfl(x2p, lg * 4 + j);

        // 16 n-tiles in groups of 4 (keeps live acc at 16 VGPRs)
#pragma unroll
        for (int g = 0; g < 4; ++g) {
            f32x4 acc[4];
#pragma unroll
            for (int tt = 0; tt < 4; ++tt) {
                acc[tt] = f32x4{0.f, 0.f, 0.f, 0.f};
                const int t = g * 4 + tt;
                acc[tt] = __builtin_amdgcn_mfma_f32_16x16x32_bf16(Af[0], Bf[t][0], acc[tt], 0, 0, 0);
                acc[tt] = __builtin_amdgcn_mfma_f32_16x16x32_bf16(Af[1], Bf[t][1], acc[tt], 0, 0, 0);
            }
#pragma unroll
            for (int tt = 0; tt < 4; ++tt) {
                const int t = g * 4 + tt;
#pragma unroll
                for (int j = 0; j < 4; ++j) {
                    const float val = x2r[j] + p2[t] - 2.f * acc[tt][j];
                    const int row = rbase + lg * 4 + j;
                    out[row * O_ + t * 16 + lr] = val;
                }
            }
        }
    }
}

extern "C" void kernel_launch(void* const* d_in, const int* in_sizes, int n_in,
                              void* d_out, int out_size, void* d_ws, size_t ws_size,
                              hipStream_t stream) {
    const float* x  = (const float*)d_in[0];   // [16,128,128,64] fp32
    const float* om = (const float*)d_in[1];   // [256,64] fp32
    float* out = (float*)d_out;                // [16,128,128,256,1] fp32

    dim3 grid(M_ / ROWS_PER_BLOCK);   // 512
    dim3 block(256);
    dist_kernel<<<grid, block, 0, stream>>>(x, om, out);
}

// Round 2
// 95.182 us; speedup vs baseline: 1.1698x; 1.1698x over previous
//
#include <hip/hip_runtime.h>

// dist[pix, o] = ||x[pix]||^2 + ||omega[o]||^2 - 2 * x.omega
// M = 262144 pixels, O = 256 protos, D = 64.
// Round-2 design: swapped-operand MFMA (A=omega, B=x) so each lane's 4-wide
// accumulator = 4 consecutive protos of one pixel -> dwordx4 stores.
// omega lives in LDS as pre-packed bf16 fragments (32KB) + p2 (1KB), shared
// by all 4 waves -> ~110 VGPR -> 4 waves/SIMD.

typedef __attribute__((ext_vector_type(4))) float f32x4;
typedef __attribute__((ext_vector_type(8))) short s16x8;
typedef __attribute__((ext_vector_type(4))) unsigned int u32x4;

constexpr int D_ = 64;
constexpr int O_ = 256;
constexpr int M_ = 16 * 128 * 128;           // 262144
constexpr int ITERS = 4;
constexpr int PIX_PER_BLOCK = 4 * 16 * ITERS; // 256
constexpr int NBLOCKS = M_ / PIX_PER_BLOCK;   // 1024

__device__ __forceinline__ unsigned short f2bf(float f) {
    // round-to-nearest-even fp32 -> bf16
    unsigned u = __builtin_bit_cast(unsigned, f);
    u += 0x7FFFu + ((u >> 16) & 1u);
    return (unsigned short)(u >> 16);
}

__global__ __launch_bounds__(256, 4) void dist_kernel(
    const float* __restrict__ x,
    const float* __restrict__ om,
    float* __restrict__ out)
{
    // [ (t*2+s)*64 + lane ] : per-lane 16B bf16 A-fragment of proto-tile t, k-step s
    __shared__ u32x4 lfrag[32 * 64];          // 32 KiB
    __shared__ __align__(16) float lp2[O_];   // 1 KiB

    const int tid  = threadIdx.x;
    const int wave = tid >> 6;
    const int lane = tid & 63;
    const int lr   = lane & 15;   // A-frag: proto-in-tile ; B-frag/out: pixel-in-tile
    const int lg   = lane >> 4;   // k-group

    // ---------- once per block: omega -> bf16 fragments + p2, into LDS ------
#pragma unroll
    for (int tt = 0; tt < 4; ++tt) {
        const int t = wave * 4 + tt;
        const float* src = om + (t * 16 + lr) * D_ + lg * 8;
        f32x4 v0 = *(const f32x4*)(src);
        f32x4 v1 = *(const f32x4*)(src + 4);
        f32x4 v2 = *(const f32x4*)(src + 32);
        f32x4 v3 = *(const f32x4*)(src + 36);
        float p2p = 0.f;
        s16x8 f0, f1;
#pragma unroll
        for (int j = 0; j < 4; ++j) {
            f0[j]     = (short)f2bf(v0[j]); p2p += v0[j] * v0[j];
            f0[4 + j] = (short)f2bf(v1[j]); p2p += v1[j] * v1[j];
            f1[j]     = (short)f2bf(v2[j]); p2p += v2[j] * v2[j];
            f1[4 + j] = (short)f2bf(v3[j]); p2p += v3[j] * v3[j];
        }
        lfrag[(t * 2 + 0) * 64 + lane] = __builtin_bit_cast(u32x4, f0);
        lfrag[(t * 2 + 1) * 64 + lane] = __builtin_bit_cast(u32x4, f1);
        p2p += __shfl_xor(p2p, 16);
        p2p += __shfl_xor(p2p, 32);
        if (lg == 0) lp2[t * 16 + lr] = p2p;   // lanes 0..15, conflict-free
    }
    __syncthreads();

    // ---------- steady state: 16 pixels per wave per iteration --------------
    const int pix0 = blockIdx.x * PIX_PER_BLOCK;
    for (int it = 0; it < ITERS; ++it) {
        const int rbase = pix0 + it * 64 + wave * 16;

        // B-frag (x): lane holds pixel (rbase+lr), k = lg*8.. (+s*32)
        const float* xs = x + (rbase + lr) * D_ + lg * 8;
        f32x4 a0 = __builtin_nontemporal_load((const f32x4*)(xs));
        f32x4 a1 = __builtin_nontemporal_load((const f32x4*)(xs + 4));
        f32x4 a2 = __builtin_nontemporal_load((const f32x4*)(xs + 32));
        f32x4 a3 = __builtin_nontemporal_load((const f32x4*)(xs + 36));
        s16x8 Bx0, Bx1;
        float x2p = 0.f;
#pragma unroll
        for (int j = 0; j < 4; ++j) {
            Bx0[j]     = (short)f2bf(a0[j]); x2p += a0[j] * a0[j];
            Bx0[4 + j] = (short)f2bf(a1[j]); x2p += a1[j] * a1[j];
            Bx1[j]     = (short)f2bf(a2[j]); x2p += a2[j] * a2[j];
            Bx1[4 + j] = (short)f2bf(a3[j]); x2p += a3[j] * a3[j];
        }
        // full ||x||^2 of pixel (rbase+lr); col of C is lr so no re-shuffle
        x2p += __shfl_xor(x2p, 16);
        x2p += __shfl_xor(x2p, 32);

        float* obase = out + (size_t)(rbase + lr) * O_;

#pragma unroll 4
        for (int t = 0; t < 16; ++t) {
            s16x8 A0 = __builtin_bit_cast(s16x8, lfrag[(t * 2 + 0) * 64 + lane]);
            s16x8 A1 = __builtin_bit_cast(s16x8, lfrag[(t * 2 + 1) * 64 + lane]);
            f32x4 acc = {0.f, 0.f, 0.f, 0.f};
            acc = __builtin_amdgcn_mfma_f32_16x16x32_bf16(A0, Bx0, acc, 0, 0, 0);
            acc = __builtin_amdgcn_mfma_f32_16x16x32_bf16(A1, Bx1, acc, 0, 0, 0);
            // C layout: row(=proto) = lg*4 + j, col(=pixel) = lr
            const f32x4 b4 = *(const f32x4*)&lp2[t * 16 + lg * 4];  // broadcast
            f32x4 val;
#pragma unroll
            for (int j = 0; j < 4; ++j)
                val[j] = (x2p + b4[j]) - 2.f * acc[j];
            __builtin_nontemporal_store(val, (f32x4*)(obase + t * 16 + lg * 4));
        }
    }
}

extern "C" void kernel_launch(void* const* d_in, const int* in_sizes, int n_in,
                              void* d_out, int out_size, void* d_ws, size_t ws_size,
                              hipStream_t stream) {
    const float* x  = (const float*)d_in[0];   // [16,128,128,64] fp32
    const float* om = (const float*)d_in[1];   // [256,64] fp32
    float* out = (float*)d_out;                // [16,128,128,256,1] fp32

    dist_kernel<<<dim3(NBLOCKS), dim3(256), 0, stream>>>(x, om, out);
}